// Round 16
// baseline (263.784 us; speedup 1.0000x reference)
//
#include <hip/hip_runtime.h>

#define N_NODES   100000
#define N_EDGES   3200000
#define N_FEAT    128
#define HIDDEN    16
#define MLP_H     100
#define N_CLASSES 12
#define N_GRAPHS  512
#define BNODES    512            // nodes per bucket (dst>>9)
#define NBUCK     196            // ceil(N_NODES/512)
#define BCAP      18400          // bucket capacity incl. per-node pad-to-4 (%16==0)
#define CPAD      16             // counter padding (ints) -> 1 counter / 64B
#define RING      48             // LDS ring slots per bucket (3 x 16-chunk)
#define BIN_BLOCKS 256
#define GEMM_BLOCKS 391          // ceil(N_NODES/256)

// ---- init: gcursor[b] = b*BCAP ; pooled = 0 -------------------------------
__global__ __launch_bounds__(256) void kInit(int* __restrict__ gcursor,
                                             float* __restrict__ pooled) {
    int t = blockIdx.x * 256 + threadIdx.x;            // grid 32*256 = 8192
    if (t < NBUCK) gcursor[t * CPAD] = t * BCAP;
    if (t < N_GRAPHS * HIDDEN) pooled[t] = 0.f;
}

// ---- fused: blocks [0,BIN_BLOCKS) bin edges; rest compute hp = x@W1 -------
__global__ __launch_bounds__(256) void kBinGemm(const int* __restrict__ src,
                                                const int* __restrict__ dst,
                                                int* __restrict__ gcursor,
                                                int* __restrict__ pairs,
                                                const float* __restrict__ x,
                                                const float* __restrict__ W1,
                                                float* __restrict__ hp) {
    __shared__ union {
        struct { int ring[NBUCK * RING]; int cnt[NBUCK]; int fl[NBUCK]; } bin;
        float gw[N_FEAT * HIDDEN];
    } sm;
    int t = threadIdx.x;
    if (blockIdx.x < BIN_BLOCKS) {
        // ------------- binning role (single-writer 64B chunk flushes) ------
        for (int i = t; i < NBUCK; i += 256) { sm.bin.cnt[i] = 0; sm.bin.fl[i] = 0; }
        __syncthreads();
        const int batch = 256 * 8;                     // 2048 edges per iter
        for (int base = blockIdx.x * batch; base < N_EDGES;
             base += BIN_BLOCKS * batch) {
            int e0 = base + t * 8;
            if (e0 < N_EDGES) {                        // N_EDGES % 8 == 0
                int4 d4a = *(const int4*)&dst[e0];
                int4 d4b = *(const int4*)&dst[e0 + 4];
                int4 s4a = *(const int4*)&src[e0];
                int4 s4b = *(const int4*)&src[e0 + 4];
                int dd[8] = {d4a.x, d4a.y, d4a.z, d4a.w,
                             d4b.x, d4b.y, d4b.z, d4b.w};
                int ss[8] = {s4a.x, s4a.y, s4a.z, s4a.w,
                             s4b.x, s4b.y, s4b.z, s4b.w};
#pragma unroll
                for (int k = 0; k < 8; ++k) {
                    int b = dd[k] >> 9;
                    int p = atomicAdd(&sm.bin.cnt[b], 1);
                    sm.bin.ring[b * RING + (p % RING)] =
                        (ss[k] << 9) | (dd[k] & 511);
                }
            }
            __syncthreads();
            if (t < NBUCK) {
                while (sm.bin.cnt[t] - sm.bin.fl[t] >= 16) {
                    int start = sm.bin.fl[t];
                    int gpos = atomicAdd(&gcursor[t * CPAD], 16);
                    int rbase = t * RING + (start % RING); // 16-aligned, 48%16==0
                    const int4* rp = (const int4*)&sm.bin.ring[rbase];
                    int4* gp = (int4*)&pairs[gpos];
                    gp[0] = rp[0]; gp[1] = rp[1]; gp[2] = rp[2]; gp[3] = rp[3];
                    sm.bin.fl[t] = start + 16;
                }
            }
            __syncthreads();
        }
        if (t < NBUCK) {
            int pending = sm.bin.cnt[t] - sm.bin.fl[t];
            if (pending > 0) {
                int gpos = atomicAdd(&gcursor[t * CPAD], pending);
                for (int k = 0; k < pending; ++k)
                    pairs[gpos + k] =
                        sm.bin.ring[t * RING + ((sm.bin.fl[t] + k) % RING)];
            }
        }
    } else {
        // ------------- gemm role: hp = x @ W1 (UNSCALED fp32) --------------
        for (int i = t; i < N_FEAT * HIDDEN; i += 256) sm.gw[i] = W1[i];
        __syncthreads();
        int n = (blockIdx.x - BIN_BLOCKS) * 256 + t;
        if (n >= N_NODES) return;
        float acc[HIDDEN];
#pragma unroll
        for (int j = 0; j < HIDDEN; ++j) acc[j] = 0.f;
        const float4* xr = (const float4*)(x + (size_t)n * N_FEAT);
#pragma unroll 4
        for (int k4 = 0; k4 < N_FEAT / 4; ++k4) {
            float4 v = xr[k4];
            float xk[4] = {v.x, v.y, v.z, v.w};
#pragma unroll
            for (int kk = 0; kk < 4; ++kk) {
                const float4* wrow = (const float4*)&sm.gw[(k4 * 4 + kk) * HIDDEN];
#pragma unroll
                for (int j4 = 0; j4 < 4; ++j4) {
                    float4 wv = wrow[j4];
                    acc[j4 * 4 + 0] += xk[kk] * wv.x;
                    acc[j4 * 4 + 1] += xk[kk] * wv.y;
                    acc[j4 * 4 + 2] += xk[kk] * wv.z;
                    acc[j4 * 4 + 3] += xk[kk] * wv.w;
                }
            }
        }
        float4* hr = (float4*)(hp + (size_t)n * HIDDEN);
#pragma unroll
        for (int j4 = 0; j4 < 4; ++j4)
            hr[j4] = make_float4(acc[j4 * 4 + 0], acc[j4 * 4 + 1],
                                 acc[j4 * 4 + 2], acc[j4 * 4 + 3]);
    }
}

// ---- per-bucket: stage, counting-sort in place into PAD4 layout ------------
// Each node's csr segment starts 16B-aligned (beg%4==0), padded to deg4 with
// -16 sentinels. odc = (padded beg, true deg). Tail: scale hp rows by dinv.
__global__ __launch_bounds__(512) void kBuild(const int* __restrict__ gcursor,
                                              int* __restrict__ pairs,
                                              int2* __restrict__ odc,
                                              float* __restrict__ hp) {
    __shared__ int lp[BCAP];             // 73600 B
    __shared__ int hist[BNODES];
    __shared__ int sc[BNODES];
    __shared__ int lcur[BNODES];
    __shared__ float dvl[BNODES];
    int b = blockIdx.x, t = threadIdx.x;
    int base = b * BCAP;
    int cnt = gcursor[b * CPAD] - base;
    for (int i = t; i < cnt; i += 512) lp[i] = pairs[base + i];
    hist[t] = 0;
    __syncthreads();
    for (int i = t; i < cnt; i += 512) atomicAdd(&hist[lp[i] & 511], 1);
    __syncthreads();
    int deg = hist[t];
    int deg4 = (deg + 3) & ~3;           // pad to multiple of 4
    sc[t] = deg4;
    __syncthreads();
    for (int s = 1; s < 512; s <<= 1) {
        int a = (t >= s) ? sc[t - s] : 0;
        __syncthreads();
        sc[t] += a;
        __syncthreads();
    }
    int g = b * BNODES + t;
    int excl = base + sc[t] - deg4;      // padded exclusive offset (%4==0)
    lcur[t] = excl;
    dvl[t] = rsqrtf((float)deg + 1.0f);  // +1 = self loop
    if (g < N_NODES) odc[g] = make_int2(excl, deg);
    __syncthreads();
    for (int i = t; i < cnt; i += 512) {
        int v = lp[i];
        int pos = atomicAdd(&lcur[v & 511], 1);
        pairs[pos] = (v >> 9) << 6;      // csr = byte offset of fp32 src row
    }
    // pad slots [deg, deg4) of this thread's node (disjoint addresses)
    for (int p = deg; p < deg4; ++p) pairs[excl + p] = -16;
    __syncthreads();
    // scale hp rows of nodes [b*512, b*512+512)
    int fbase = b * BNODES * HIDDEN;
#pragma unroll
    for (int i = 0; i < 16; ++i) {
        int f = i * 512 + t;
        int gi = fbase + f;
        if (gi < N_NODES * HIDDEN) hp[gi] *= dvl[f >> 4];
    }
}

// ---- CSR gather-aggregate (fp32), zero-shfl, 2-deep pipelined --------------
// 16 lanes/node: lane = eq(edge slot 0..3) x jj(feature quad 0..3).
// Per iter: 2 int4 idx loads (next 32 edges) + 8 float4 gathers in flight.
// aggval_j = (hp[n][j] + sum_s hp[s][j]) * dinv[n],  dinv = rsqrt(deg+1)
// MODE 1: out = dinv[n] * sum_k relu(aggval_k + b1[k]) * W2[k][j]
// MODE 0: val = relu(aggval_j + b2[j]); block pool over 16 nodes -> pooled
template <int MODE>
__global__ __launch_bounds__(256)
void kAgg(const float* __restrict__ hp, const int2* __restrict__ odc,
          const int* __restrict__ csr, const float* __restrict__ W2,
          const float* __restrict__ bias, float* __restrict__ outbuf,
          const int* __restrict__ batch, float* __restrict__ pooled) {
    __shared__ float W2s[HIDDEN * HIDDEN];
    __shared__ float bs[HIDDEN];
    __shared__ float red[256];
    __shared__ int sseg[2];
    int t = threadIdx.x;
    if (MODE == 1) W2s[t] = W2[t];       // block = 256 = HIDDEN*HIDDEN
    if (t < HIDDEN) bs[t] = bias[t];
    int n0 = blockIdx.x * 16;
    if (MODE == 0) {
        if (t == 0) sseg[0] = batch[n0];
        if (t == 1) sseg[1] = batch[n0 + 15];
    }
    __syncthreads();

    int gid = blockIdx.x * 256 + t;
    int n = gid >> 4;                    // N_NODES % 16 == 0, no tail
    int l16 = gid & 15;
    int jj = l16 & 3;                    // feature quad -> bytes jj*16
    int eq = l16 >> 2;                   // edge slot (4 consecutive edges)
    int2 oc = odc[n];
    int beg = oc.x, deg = oc.y;          // beg % 4 == 0 (pad4 layout)
    int deg4 = (deg + 3) & ~3;
    const char* hpc = (const char*)hp;
    const int4* csr4 = (const int4*)csr;
    int c4 = (beg >> 2) + eq;
    int jb = jj << 4;
    float4 a4 = make_float4(0.f, 0.f, 0.f, 0.f);
    const int4 msent = make_int4(-16, -16, -16, -16);
    const float4 z4 = make_float4(0.f, 0.f, 0.f, 0.f);

    int e4 = eq * 4;
    int4 i4a = (e4 < deg4)      ? csr4[c4]     : msent;
    int4 i4b = (e4 + 16 < deg4) ? csr4[c4 + 4] : msent;
    for (int cur = 0; cur < deg4; cur += 32) {
        int nxt = cur + 32;
        int4 p4a = (nxt + e4 < deg4)      ? csr4[c4 + (nxt >> 2)]     : msent;
        int4 p4b = (nxt + e4 + 16 < deg4) ? csr4[c4 + (nxt >> 2) + 4] : msent;
        float4 v0 = (i4a.x >= 0) ? *(const float4*)(hpc + i4a.x + jb) : z4;
        float4 v1 = (i4a.y >= 0) ? *(const float4*)(hpc + i4a.y + jb) : z4;
        float4 v2 = (i4a.z >= 0) ? *(const float4*)(hpc + i4a.z + jb) : z4;
        float4 v3 = (i4a.w >= 0) ? *(const float4*)(hpc + i4a.w + jb) : z4;
        float4 v4 = (i4b.x >= 0) ? *(const float4*)(hpc + i4b.x + jb) : z4;
        float4 v5 = (i4b.y >= 0) ? *(const float4*)(hpc + i4b.y + jb) : z4;
        float4 v6 = (i4b.z >= 0) ? *(const float4*)(hpc + i4b.z + jb) : z4;
        float4 v7 = (i4b.w >= 0) ? *(const float4*)(hpc + i4b.w + jb) : z4;
        a4.x += v0.x + v1.x + v2.x + v3.x + v4.x + v5.x + v6.x + v7.x;
        a4.y += v0.y + v1.y + v2.y + v3.y + v4.y + v5.y + v6.y + v7.y;
        a4.z += v0.z + v1.z + v2.z + v3.z + v4.z + v5.z + v6.z + v7.z;
        a4.w += v0.w + v1.w + v2.w + v3.w + v4.w + v5.w + v6.w + v7.w;
        i4a = p4a; i4b = p4b;
    }
    // combine the 4 edge slots (bits 2-3 within the 16-lane group)
    a4.x += __shfl_xor(a4.x, 4, 16);  a4.y += __shfl_xor(a4.y, 4, 16);
    a4.z += __shfl_xor(a4.z, 4, 16);  a4.w += __shfl_xor(a4.w, 4, 16);
    a4.x += __shfl_xor(a4.x, 8, 16);  a4.y += __shfl_xor(a4.y, 8, 16);
    a4.z += __shfl_xor(a4.z, 8, 16);  a4.w += __shfl_xor(a4.w, 8, 16);
    // remap: feature l16 = component (l16&3) of group-lane (l16>>2)
    int srcl = l16 >> 2;
    float c0 = __shfl(a4.x, srcl, 16);
    float c1 = __shfl(a4.y, srcl, 16);
    float c2 = __shfl(a4.z, srcl, 16);
    float c3 = __shfl(a4.w, srcl, 16);
    int cc = l16 & 3;
    float acc = (cc == 0) ? c0 : (cc == 1) ? c1 : (cc == 2) ? c2 : c3;
    acc += hp[(size_t)n * HIDDEN + l16];   // self loop
    float dv = rsqrtf((float)deg + 1.0f);
    if (MODE == 1) {
        float tt = fmaxf(acc * dv + bs[l16], 0.f);
        float o = 0.f;
#pragma unroll
        for (int k = 0; k < 16; ++k)
            o += __shfl(tt, k, 16) * W2s[k * HIDDEN + l16];
        outbuf[(size_t)n * HIDDEN + l16] = o * dv;
    } else {
        float val = fmaxf(acc * dv + bs[l16], 0.f);
        int ln = t >> 4;
        red[t] = val;
        __syncthreads();
        if (sseg[0] == sseg[1]) {          // 16 nodes in one graph (common)
            if (ln < 8) red[t] += red[t + 128];
            __syncthreads();
            if (ln < 4) red[t] += red[t + 64];
            __syncthreads();
            if (ln < 2) red[t] += red[t + 32];
            __syncthreads();
            if (ln == 0)
                unsafeAtomicAdd(&pooled[(size_t)sseg[0] * HIDDEN + l16],
                                red[t] + red[t + 16]);
        } else {
            unsafeAtomicAdd(&pooled[(size_t)batch[n] * HIDDEN + l16], val);
        }
    }
}

// ------- g=relu(pooled); g1=relu(g@lw1+lb1); out=g1@lw2+lb2 ----------------
__global__ __launch_bounds__(64) void kMlp(const float* __restrict__ pooled,
                                           const float* __restrict__ lw1,
                                           const float* __restrict__ lb1,
                                           const float* __restrict__ lw2,
                                           const float* __restrict__ lb2,
                                           float* __restrict__ out) {
    int g = blockIdx.x * 64 + threadIdx.x;
    if (g >= N_GRAPHS) return;
    float gv[HIDDEN];
#pragma unroll
    for (int k = 0; k < HIDDEN; ++k)
        gv[k] = fmaxf(pooled[(size_t)g * HIDDEN + k], 0.f);
    float o[N_CLASSES];
#pragma unroll
    for (int c = 0; c < N_CLASSES; ++c) o[c] = lb2[c];
    for (int j = 0; j < MLP_H; ++j) {
        float s = lb1[j];
#pragma unroll
        for (int k = 0; k < HIDDEN; ++k) s += gv[k] * lw1[k * MLP_H + j];
        s = fmaxf(s, 0.f);
#pragma unroll
        for (int c = 0; c < N_CLASSES; ++c) o[c] += s * lw2[j * N_CLASSES + c];
    }
#pragma unroll
    for (int c = 0; c < N_CLASSES; ++c) out[(size_t)g * N_CLASSES + c] = o[c];
}

extern "C" void kernel_launch(void* const* d_in, const int* in_sizes, int n_in,
                              void* d_out, int out_size, void* d_ws,
                              size_t ws_size, hipStream_t stream) {
    const float* x     = (const float*)d_in[0];
    const int*   ei    = (const int*)d_in[1];
    const int*   batch = (const int*)d_in[2];
    const float* W1    = (const float*)d_in[3];
    const float* b1    = (const float*)d_in[4];
    const float* W2    = (const float*)d_in[5];
    const float* b2    = (const float*)d_in[6];
    const float* lw1   = (const float*)d_in[7];
    const float* lb1   = (const float*)d_in[8];
    const float* lw2   = (const float*)d_in[9];
    const float* lb2   = (const float*)d_in[10];
    float* out = (float*)d_out;

    const int* src = ei;
    const int* dst = ei + N_EDGES;

    // workspace layout (bytes) — total 28,074,752 (ws ~256 MB per harness fill)
    char*  ws      = (char*)d_ws;
    int*   gcursor = (int*)(ws + 0);           // 12544 -> 16384
    int2*  odc     = (int2*)(ws + 16384);      // 800000 (padded off, deg)
    int*   pairs   = (int*)(ws + 816384);      // 196*18400*4 = 14425600 (=csr)
    float* hp      = (float*)(ws + 15241984);  // 6400000
    float* hp2     = (float*)(ws + 21641984);  // 6400000
    float* pooled  = (float*)(ws + 28041984);  // 32768

    kInit<<<32, 256, 0, stream>>>(gcursor, pooled);
    kBinGemm<<<BIN_BLOCKS + GEMM_BLOCKS, 256, 0, stream>>>(
        src, dst, gcursor, pairs, x, W1, hp);
    kBuild<<<NBUCK, 512, 0, stream>>>(gcursor, pairs, odc, hp);
    // layer1 aggregate + layer2 transform fused -> hp2
    kAgg<1><<<N_NODES / 16, 256, 0, stream>>>(hp, odc, pairs, W2, b1, hp2,
                                              nullptr, nullptr);
    // layer2 aggregate + relu(+b2) + fused pool -> pooled
    kAgg<0><<<N_NODES / 16, 256, 0, stream>>>(hp2, odc, pairs, nullptr, b2,
                                              nullptr, batch, pooled);
    kMlp<<<(N_GRAPHS + 63) / 64, 64, 0, stream>>>(pooled, lw1, lb1, lw2, lb2, out);
}

// Round 17
// 161.200 us; speedup vs baseline: 1.6364x; 1.6364x over previous
//
#include <hip/hip_runtime.h>

#define N_NODES   100000
#define N_EDGES   3200000
#define N_FEAT    128
#define HIDDEN    16
#define MLP_H     100
#define N_CLASSES 12
#define N_GRAPHS  512
#define BNODES    512            // nodes per bucket (dst>>9)
#define NBUCK     196            // ceil(N_NODES/512)
#define BCAP      17328          // bucket capacity (mean 16327 + 7.8 sigma), %16==0
#define CPAD      16             // counter padding (ints) -> 1 counter / 64B
#define RING      64             // LDS ring slots per bucket in kBin
#define BIN_BLOCKS 256
#define GEMM_BLOCKS 391          // ceil(N_NODES/256)

// ---- init: gcursor[b] = b*BCAP ; pooled = 0 -------------------------------
__global__ __launch_bounds__(256) void kInit(int* __restrict__ gcursor,
                                             float* __restrict__ pooled) {
    int t = blockIdx.x * 256 + threadIdx.x;            // grid 32*256 = 8192
    if (t < NBUCK) gcursor[t * CPAD] = t * BCAP;
    if (t < N_GRAPHS * HIDDEN) pooled[t] = 0.f;
}

// ---- fused: blocks [0,BIN_BLOCKS) bin edges; rest compute hp = x@W1 -------
__global__ __launch_bounds__(256) void kBinGemm(const int* __restrict__ src,
                                                const int* __restrict__ dst,
                                                int* __restrict__ gcursor,
                                                int* __restrict__ pairs,
                                                const float* __restrict__ x,
                                                const float* __restrict__ W1,
                                                float* __restrict__ hp) {
    __shared__ union {
        struct { int ring[NBUCK * RING]; int cnt[NBUCK]; int fl[NBUCK]; } bin;
        float gw[N_FEAT * HIDDEN];
    } sm;
    int t = threadIdx.x;
    if (blockIdx.x < BIN_BLOCKS) {
        // ------------- binning role (single-writer 64B chunk flushes) ------
        for (int i = t; i < NBUCK; i += 256) { sm.bin.cnt[i] = 0; sm.bin.fl[i] = 0; }
        __syncthreads();
        const int batch = 256 * 8;                     // 2048 edges per iter
        for (int base = blockIdx.x * batch; base < N_EDGES;
             base += BIN_BLOCKS * batch) {
            int e0 = base + t * 8;
            if (e0 < N_EDGES) {                        // N_EDGES % 8 == 0
                int4 d4a = *(const int4*)&dst[e0];
                int4 d4b = *(const int4*)&dst[e0 + 4];
                int4 s4a = *(const int4*)&src[e0];
                int4 s4b = *(const int4*)&src[e0 + 4];
                int dd[8] = {d4a.x, d4a.y, d4a.z, d4a.w,
                             d4b.x, d4b.y, d4b.z, d4b.w};
                int ss[8] = {s4a.x, s4a.y, s4a.z, s4a.w,
                             s4b.x, s4b.y, s4b.z, s4b.w};
#pragma unroll
                for (int k = 0; k < 8; ++k) {
                    int b = dd[k] >> 9;
                    int p = atomicAdd(&sm.bin.cnt[b], 1);
                    sm.bin.ring[b * RING + (p & (RING - 1))] =
                        (ss[k] << 9) | (dd[k] & 511);
                }
            }
            __syncthreads();
            if (t < NBUCK) {
                while (sm.bin.cnt[t] - sm.bin.fl[t] >= 16) {
                    int start = sm.bin.fl[t];
                    int gpos = atomicAdd(&gcursor[t * CPAD], 16);
                    int rbase = t * RING + (start & (RING - 1));
                    const int4* rp = (const int4*)&sm.bin.ring[rbase];
                    int4* gp = (int4*)&pairs[gpos];
                    gp[0] = rp[0]; gp[1] = rp[1]; gp[2] = rp[2]; gp[3] = rp[3];
                    sm.bin.fl[t] = start + 16;
                }
            }
            __syncthreads();
        }
        if (t < NBUCK) {
            int pending = sm.bin.cnt[t] - sm.bin.fl[t];
            if (pending > 0) {
                int gpos = atomicAdd(&gcursor[t * CPAD], pending);
                for (int k = 0; k < pending; ++k)
                    pairs[gpos + k] =
                        sm.bin.ring[t * RING + ((sm.bin.fl[t] + k) & (RING - 1))];
            }
        }
    } else {
        // ------------- gemm role: hp = x @ W1 (UNSCALED fp32) --------------
        for (int i = t; i < N_FEAT * HIDDEN; i += 256) sm.gw[i] = W1[i];
        __syncthreads();
        int n = (blockIdx.x - BIN_BLOCKS) * 256 + t;
        if (n >= N_NODES) return;
        float acc[HIDDEN];
#pragma unroll
        for (int j = 0; j < HIDDEN; ++j) acc[j] = 0.f;
        const float4* xr = (const float4*)(x + (size_t)n * N_FEAT);
#pragma unroll 4
        for (int k4 = 0; k4 < N_FEAT / 4; ++k4) {
            float4 v = xr[k4];
            float xk[4] = {v.x, v.y, v.z, v.w};
#pragma unroll
            for (int kk = 0; kk < 4; ++kk) {
                const float4* wrow = (const float4*)&sm.gw[(k4 * 4 + kk) * HIDDEN];
#pragma unroll
                for (int j4 = 0; j4 < 4; ++j4) {
                    float4 wv = wrow[j4];
                    acc[j4 * 4 + 0] += xk[kk] * wv.x;
                    acc[j4 * 4 + 1] += xk[kk] * wv.y;
                    acc[j4 * 4 + 2] += xk[kk] * wv.z;
                    acc[j4 * 4 + 3] += xk[kk] * wv.w;
                }
            }
        }
        float4* hr = (float4*)(hp + (size_t)n * HIDDEN);
#pragma unroll
        for (int j4 = 0; j4 < 4; ++j4)
            hr[j4] = make_float4(acc[j4 * 4 + 0], acc[j4 * 4 + 1],
                                 acc[j4 * 4 + 2], acc[j4 * 4 + 3]);
    }
}

// ---- per-bucket: stage, counting-sort in place -> csr(byteoff); odc;
// ---- then scale this bucket's hp rows by dinv ------------------------------
__global__ __launch_bounds__(512) void kBuild(const int* __restrict__ gcursor,
                                              int* __restrict__ pairs,
                                              int2* __restrict__ odc,
                                              float* __restrict__ hp) {
    __shared__ int lp[BCAP];             // 69312 B
    __shared__ int hist[BNODES];
    __shared__ int sc[BNODES];
    __shared__ int lcur[BNODES];
    __shared__ float dvl[BNODES];
    int b = blockIdx.x, t = threadIdx.x;
    int base = b * BCAP;
    int cnt = gcursor[b * CPAD] - base;
    for (int i = t; i < cnt; i += 512) lp[i] = pairs[base + i];
    hist[t] = 0;
    __syncthreads();
    for (int i = t; i < cnt; i += 512) atomicAdd(&hist[lp[i] & 511], 1);
    __syncthreads();
    sc[t] = hist[t];
    __syncthreads();
    for (int s = 1; s < 512; s <<= 1) {
        int a = (t >= s) ? sc[t - s] : 0;
        __syncthreads();
        sc[t] += a;
        __syncthreads();
    }
    int g = b * BNODES + t;
    int excl = base + sc[t] - hist[t];
    lcur[t] = excl;
    dvl[t] = rsqrtf((float)hist[t] + 1.0f);  // +1 = self loop
    if (g < N_NODES) odc[g] = make_int2(excl, hist[t]);
    __syncthreads();
    for (int i = t; i < cnt; i += 512) {
        int v = lp[i];
        int pos = atomicAdd(&lcur[v & 511], 1);
        pairs[pos] = (v >> 9) << 6;      // csr = byte offset of fp32 src row
    }
    __syncthreads();
    // scale hp rows of nodes [b*512, b*512+512)
    int fbase = b * BNODES * HIDDEN;
#pragma unroll
    for (int i = 0; i < 16; ++i) {
        int f = i * 512 + t;
        int gi = fbase + f;
        if (gi < N_NODES * HIDDEN) hp[gi] *= dvl[f >> 4];
    }
}

// ---- CSR gather-aggregate (fp32), float4 gathers ---------------------------
// 16 lanes/node: lane = eq(edge slot 0..3) x jj(feature quad 0..3).
// Each gather instr loads 16 rows per wave; 32-edge pipelined batches.
// aggval_j = (hp[n][j] + sum_s hp[s][j]) * dinv[n],  dinv = rsqrt(deg+1)
// MODE 1: out = dinv[n] * sum_k relu(aggval_k + b1[k]) * W2[k][j]
// MODE 0: val = relu(aggval_j + b2[j]); block pool over 16 nodes -> pooled
template <int MODE>
__global__ __launch_bounds__(256)
void kAgg(const float* __restrict__ hp, const int2* __restrict__ odc,
          const int* __restrict__ csr, const float* __restrict__ W2,
          const float* __restrict__ bias, float* __restrict__ outbuf,
          const int* __restrict__ batch, float* __restrict__ pooled) {
    __shared__ float W2s[HIDDEN * HIDDEN];
    __shared__ float bs[HIDDEN];
    __shared__ float red[256];
    __shared__ int sseg[2];
    int t = threadIdx.x;
    if (MODE == 1) W2s[t] = W2[t];       // block = 256 = HIDDEN*HIDDEN
    if (t < HIDDEN) bs[t] = bias[t];
    int n0 = blockIdx.x * 16;
    if (MODE == 0) {
        if (t == 0) sseg[0] = batch[n0];
        if (t == 1) sseg[1] = batch[n0 + 15];
    }
    __syncthreads();

    int gid = blockIdx.x * 256 + t;
    int n = gid >> 4;                    // N_NODES % 16 == 0, no tail
    int l16 = gid & 15;
    int jj = l16 & 3;                    // feature quad -> bytes jj*16
    int eq = l16 >> 2;                   // edge slot
    int2 oc = odc[n];
    int beg = oc.x, deg = oc.y;
    int end = beg + deg;
    const char* hpc = (const char*)hp;
    int jb = jj << 4;
    float4 a4 = make_float4(0.f, 0.f, 0.f, 0.f);

    int pv0 = (beg + l16 < end)      ? csr[beg + l16]      : -1;
    int pv1 = (beg + 16 + l16 < end) ? csr[beg + 16 + l16] : -1;
    for (int cur = beg; cur < end; cur += 32) {
        int nxt = cur + 32;
        int pn0 = (nxt + l16 < end)      ? csr[nxt + l16]      : -1;
        int pn1 = (nxt + 16 + l16 < end) ? csr[nxt + 16 + l16] : -1;
        int sb[8];
#pragma unroll
        for (int k = 0; k < 4; ++k) {
            sb[k]     = __shfl(pv0, k * 4 + eq, 16);
            sb[4 + k] = __shfl(pv1, k * 4 + eq, 16);
        }
        float4 v[8];
#pragma unroll
        for (int q = 0; q < 8; ++q)
            v[q] = (sb[q] >= 0) ? *(const float4*)(hpc + sb[q] + jb)
                                : make_float4(0.f, 0.f, 0.f, 0.f);
#pragma unroll
        for (int q = 0; q < 8; ++q) {
            a4.x += v[q].x; a4.y += v[q].y; a4.z += v[q].z; a4.w += v[q].w;
        }
        pv0 = pn0; pv1 = pn1;
    }
    // combine the 4 edge slots (bits 2-3 within the 16-lane group)
    a4.x += __shfl_xor(a4.x, 4, 16);  a4.y += __shfl_xor(a4.y, 4, 16);
    a4.z += __shfl_xor(a4.z, 4, 16);  a4.w += __shfl_xor(a4.w, 4, 16);
    a4.x += __shfl_xor(a4.x, 8, 16);  a4.y += __shfl_xor(a4.y, 8, 16);
    a4.z += __shfl_xor(a4.z, 8, 16);  a4.w += __shfl_xor(a4.w, 8, 16);
    // remap: feature l16 = component (l16&3) of group-lane (l16>>2)
    int srcl = l16 >> 2;
    float c0 = __shfl(a4.x, srcl, 16);
    float c1 = __shfl(a4.y, srcl, 16);
    float c2 = __shfl(a4.z, srcl, 16);
    float c3 = __shfl(a4.w, srcl, 16);
    int cc = l16 & 3;
    float acc = (cc == 0) ? c0 : (cc == 1) ? c1 : (cc == 2) ? c2 : c3;
    acc += hp[(size_t)n * HIDDEN + l16];   // self loop
    float dv = rsqrtf((float)deg + 1.0f);
    if (MODE == 1) {
        float tt = fmaxf(acc * dv + bs[l16], 0.f);
        float o = 0.f;
#pragma unroll
        for (int k = 0; k < 16; ++k)
            o += __shfl(tt, k, 16) * W2s[k * HIDDEN + l16];
        outbuf[(size_t)n * HIDDEN + l16] = o * dv;
    } else {
        float val = fmaxf(acc * dv + bs[l16], 0.f);
        int ln = t >> 4;
        red[t] = val;
        __syncthreads();
        if (sseg[0] == sseg[1]) {          // 16 nodes in one graph (common)
            if (ln < 8) red[t] += red[t + 128];
            __syncthreads();
            if (ln < 4) red[t] += red[t + 64];
            __syncthreads();
            if (ln < 2) red[t] += red[t + 32];
            __syncthreads();
            if (ln == 0)
                unsafeAtomicAdd(&pooled[(size_t)sseg[0] * HIDDEN + l16],
                                red[t] + red[t + 16]);
        } else {
            unsafeAtomicAdd(&pooled[(size_t)batch[n] * HIDDEN + l16], val);
        }
    }
}

// ------- g=relu(pooled); g1=relu(g@lw1+lb1); out=g1@lw2+lb2 ----------------
__global__ __launch_bounds__(64) void kMlp(const float* __restrict__ pooled,
                                           const float* __restrict__ lw1,
                                           const float* __restrict__ lb1,
                                           const float* __restrict__ lw2,
                                           const float* __restrict__ lb2,
                                           float* __restrict__ out) {
    int g = blockIdx.x * 64 + threadIdx.x;
    if (g >= N_GRAPHS) return;
    float gv[HIDDEN];
#pragma unroll
    for (int k = 0; k < HIDDEN; ++k)
        gv[k] = fmaxf(pooled[(size_t)g * HIDDEN + k], 0.f);
    float o[N_CLASSES];
#pragma unroll
    for (int c = 0; c < N_CLASSES; ++c) o[c] = lb2[c];
    for (int j = 0; j < MLP_H; ++j) {
        float s = lb1[j];
#pragma unroll
        for (int k = 0; k < HIDDEN; ++k) s += gv[k] * lw1[k * MLP_H + j];
        s = fmaxf(s, 0.f);
#pragma unroll
        for (int c = 0; c < N_CLASSES; ++c) o[c] += s * lw2[j * N_CLASSES + c];
    }
#pragma unroll
    for (int c = 0; c < N_CLASSES; ++c) out[(size_t)g * N_CLASSES + c] = o[c];
}

extern "C" void kernel_launch(void* const* d_in, const int* in_sizes, int n_in,
                              void* d_out, int out_size, void* d_ws,
                              size_t ws_size, hipStream_t stream) {
    const float* x     = (const float*)d_in[0];
    const int*   ei    = (const int*)d_in[1];
    const int*   batch = (const int*)d_in[2];
    const float* W1    = (const float*)d_in[3];
    const float* b1    = (const float*)d_in[4];
    const float* W2    = (const float*)d_in[5];
    const float* b2    = (const float*)d_in[6];
    const float* lw1   = (const float*)d_in[7];
    const float* lb1   = (const float*)d_in[8];
    const float* lw2   = (const float*)d_in[9];
    const float* lb2   = (const float*)d_in[10];
    float* out = (float*)d_out;

    const int* src = ei;
    const int* dst = ei + N_EDGES;

    // workspace layout (bytes) — total 27,234,304
    char*  ws      = (char*)d_ws;
    int*   gcursor = (int*)(ws + 0);           // 12544 -> 16384
    int2*  odc     = (int2*)(ws + 16384);      // 800000 (off,cnt per node)
    int*   pairs   = (int*)(ws + 816384);      // 196*17328*4 = 13585152 (=csr)
    float* hp      = (float*)(ws + 14401536);  // 6400000
    float* hp2     = (float*)(ws + 20801536);  // 6400000
    float* pooled  = (float*)(ws + 27201536);  // 32768

    kInit<<<32, 256, 0, stream>>>(gcursor, pooled);
    kBinGemm<<<BIN_BLOCKS + GEMM_BLOCKS, 256, 0, stream>>>(
        src, dst, gcursor, pairs, x, W1, hp);
    kBuild<<<NBUCK, 512, 0, stream>>>(gcursor, pairs, odc, hp);
    // layer1 aggregate + layer2 transform fused -> hp2
    kAgg<1><<<N_NODES / 16, 256, 0, stream>>>(hp, odc, pairs, W2, b1, hp2,
                                              nullptr, nullptr);
    // layer2 aggregate + relu(+b2) + fused pool -> pooled
    kAgg<0><<<N_NODES / 16, 256, 0, stream>>>(hp2, odc, pairs, nullptr, b2,
                                              nullptr, batch, pooled);
    kMlp<<<(N_GRAPHS + 63) / 64, 64, 0, stream>>>(pooled, lw1, lb1, lw2, lb2, out);
}